// Round 4
// baseline (484.376 us; speedup 1.0000x reference)
//
#include <hip/hip_runtime.h>
#include <math.h>

#define MAXDEG 64

// -------------------- bf16 helpers --------------------
static __device__ inline float bf2f(unsigned short u) {
    return __uint_as_float(((unsigned int)u) << 16);
}
static __device__ inline unsigned short f2bf(float f) {
    unsigned int u = __float_as_uint(f);
    u += 0x7FFFu + ((u >> 16) & 1u);  // round-nearest-even
    return (unsigned short)(u >> 16);
}
static __device__ inline float4 ld_f4(const float* p) { return *(const float4*)p; }

// -------------------- shared GEMM phases --------------------
// sA (64x128 fp32 in LDS) @ W (128x128) -> Y (bf16), 256 threads
static __device__ __forceinline__ void gemm128_phase(
    const float* sA, const float* __restrict__ W,
    unsigned short* __restrict__ Y, int row0, int t, int N) {
    int tx = t & 31, ty = t >> 5;
    int c0 = tx * 4, r0 = ty * 8;
    float acc[8][4];
#pragma unroll
    for (int i = 0; i < 8; ++i)
#pragma unroll
        for (int c = 0; c < 4; ++c) acc[i][c] = 0.f;

    for (int j = 0; j < 128; j += 4) {
        float w[4][4];
#pragma unroll
        for (int q = 0; q < 4; ++q) {
            float4 t4 = ld_f4(&W[(size_t)(j + q) * 128 + c0]);
            w[q][0] = t4.x; w[q][1] = t4.y; w[q][2] = t4.z; w[q][3] = t4.w;
        }
#pragma unroll
        for (int i = 0; i < 8; ++i) {
            float4 a4 = ld_f4(&sA[(r0 + i) * 128 + j]);
            float a[4] = {a4.x, a4.y, a4.z, a4.w};
#pragma unroll
            for (int q = 0; q < 4; ++q)
#pragma unroll
                for (int c = 0; c < 4; ++c)
                    acc[i][c] = fmaf(a[q], w[q][c], acc[i][c]);
        }
    }
#pragma unroll
    for (int i = 0; i < 8; ++i) {
        int grow = row0 + r0 + i;
        if (grow < N) {
            ushort4 o;
            o.x = f2bf(acc[i][0]); o.y = f2bf(acc[i][1]);
            o.z = f2bf(acc[i][2]); o.w = f2bf(acc[i][3]);
            *(ushort4*)&Y[(size_t)grow * 128 + c0] = o;
        }
    }
}

// sA (64x128 fp32 in LDS) @ W2 (128x40) -> Y3 (bf16), 256 threads
static __device__ __forceinline__ void gemm40_phase(
    const float* sA, const float* __restrict__ W2,
    unsigned short* __restrict__ Y3, int row0, int t, int N) {
    int tx = t & 15, ty = t >> 4;
    int c0 = tx * 4, r0 = ty * 4;
    if (tx >= 10) return;
    float acc[4][4];
#pragma unroll
    for (int i = 0; i < 4; ++i)
#pragma unroll
        for (int c = 0; c < 4; ++c) acc[i][c] = 0.f;

    for (int j = 0; j < 128; j += 4) {
        float w[4][4];
#pragma unroll
        for (int q = 0; q < 4; ++q) {
            float4 t4 = ld_f4(&W2[(size_t)(j + q) * 40 + c0]);
            w[q][0] = t4.x; w[q][1] = t4.y; w[q][2] = t4.z; w[q][3] = t4.w;
        }
#pragma unroll
        for (int i = 0; i < 4; ++i) {
            float4 a4 = ld_f4(&sA[(r0 + i) * 128 + j]);
            float a[4] = {a4.x, a4.y, a4.z, a4.w};
#pragma unroll
            for (int q = 0; q < 4; ++q)
#pragma unroll
                for (int c = 0; c < 4; ++c)
                    acc[i][c] = fmaf(a[q], w[q][c], acc[i][c]);
        }
    }
#pragma unroll
    for (int i = 0; i < 4; ++i) {
        int grow = row0 + r0 + i;
        if (grow < N) {
            ushort4 o;
            o.x = f2bf(acc[i][0]); o.y = f2bf(acc[i][1]);
            o.z = f2bf(acc[i][2]); o.w = f2bf(acc[i][3]);
            *(ushort4*)&Y3[(size_t)grow * 40 + c0] = o;
        }
    }
}

// ==================== K1: CSR build (indeg only) || GEMM1 ====================
static __global__ __launch_bounds__(256) void csr_gemm1_kernel(
    const float* __restrict__ A, const float* __restrict__ W,
    unsigned short* __restrict__ Y,
    const int* __restrict__ src, const int* __restrict__ dst,
    int* __restrict__ indeg, int* __restrict__ csr,
    int N, int E, int gG, int gE) {
    __shared__ float sA[64 * 128];
    int bid = blockIdx.x;
    int t = threadIdx.x;

    int m = gG < gE ? gG : gE;
    int role, idx;
    if (bid < 2 * m) { role = bid & 1; idx = bid >> 1; }
    else { idx = m + (bid - 2 * m); role = (gG > gE) ? 0 : 1; }

    if (role == 1) {
        int base = idx * 2048 + t * 8;
        if (base + 8 <= E) {
            int4 s0 = *(const int4*)&src[base];
            int4 s1 = *(const int4*)&src[base + 4];
            int4 d0 = *(const int4*)&dst[base];
            int4 d1 = *(const int4*)&dst[base + 4];
            int p;
            p = atomicAdd(&indeg[d0.x], 1); if (p < MAXDEG) csr[d0.x * MAXDEG + p] = s0.x;
            p = atomicAdd(&indeg[d0.y], 1); if (p < MAXDEG) csr[d0.y * MAXDEG + p] = s0.y;
            p = atomicAdd(&indeg[d0.z], 1); if (p < MAXDEG) csr[d0.z * MAXDEG + p] = s0.z;
            p = atomicAdd(&indeg[d0.w], 1); if (p < MAXDEG) csr[d0.w * MAXDEG + p] = s0.w;
            p = atomicAdd(&indeg[d1.x], 1); if (p < MAXDEG) csr[d1.x * MAXDEG + p] = s1.x;
            p = atomicAdd(&indeg[d1.y], 1); if (p < MAXDEG) csr[d1.y * MAXDEG + p] = s1.y;
            p = atomicAdd(&indeg[d1.z], 1); if (p < MAXDEG) csr[d1.z * MAXDEG + p] = s1.z;
            p = atomicAdd(&indeg[d1.w], 1); if (p < MAXDEG) csr[d1.w * MAXDEG + p] = s1.w;
        } else {
            for (int e = base; e < E; ++e) {
                int s = src[e], d = dst[e];
                int p = atomicAdd(&indeg[d], 1);
                if (p < MAXDEG) csr[d * MAXDEG + p] = s;
            }
        }
        return;
    }

    // ---- gemm1 ----
    int row0 = idx * 64;
#pragma unroll
    for (int i = 0; i < 8; ++i) {
        int fi = i * 256 + t;
        int r = fi >> 5;
        int c4 = (fi & 31) * 4;
        int grow = row0 + r;
        float4 v = make_float4(0.f, 0.f, 0.f, 0.f);
        if (grow < N) v = ld_f4(&A[(size_t)grow * 128 + c4]);
        *(float4*)&sA[r * 128 + c4] = v;
    }
    __syncthreads();
    gemm128_phase(sA, W, Y, row0, t, N);
}

// ==================== K2: outdeg histogram || agg(Y1)+relu @ Wh ====================
static __global__ __launch_bounds__(256) void hist_agggemm2_kernel(
    const unsigned short* __restrict__ Y1, const float* __restrict__ Wh,
    unsigned short* __restrict__ Y2,
    const int* __restrict__ csr, const int* __restrict__ indeg,
    const int* __restrict__ src, int* __restrict__ outdeg,
    int N, int E, int gG, int gE) {
    __shared__ float sA[64 * 128];
    int bid = blockIdx.x;
    int t = threadIdx.x;

    int m = gG < gE ? gG : gE;
    int role, idx;
    if (bid < 2 * m) { role = bid & 1; idx = bid >> 1; }
    else { idx = m + (bid - 2 * m); role = (gG > gE) ? 0 : 1; }

    if (role == 1) {
        int base = idx * 2048 + t * 8;
        if (base + 8 <= E) {
            int4 s0 = *(const int4*)&src[base];
            int4 s1 = *(const int4*)&src[base + 4];
            atomicAdd(&outdeg[s0.x], 1); atomicAdd(&outdeg[s0.y], 1);
            atomicAdd(&outdeg[s0.z], 1); atomicAdd(&outdeg[s0.w], 1);
            atomicAdd(&outdeg[s1.x], 1); atomicAdd(&outdeg[s1.y], 1);
            atomicAdd(&outdeg[s1.z], 1); atomicAdd(&outdeg[s1.w], 1);
        } else {
            for (int e = base; e < E; ++e) atomicAdd(&outdeg[src[e]], 1);
        }
        return;
    }

    // ---- agg(Y1) + relu, staged into LDS ----
    int w = t >> 6, lane = t & 63;
    int row0 = idx * 64;
    for (int i = 0; i < 16; ++i) {
        int r = w * 16 + i;
        int node = row0 + r;
        float a0 = 0.f, a1 = 0.f;
        if (node < N) {
            int d = indeg[node];
            if (d > MAXDEG) d = MAXDEG;
            int sle = (lane < d) ? csr[node * MAXDEG + lane] : 0;
            int e = 0;
            for (; e + 4 <= d; e += 4) {
                int s0 = __shfl(sle, e), s1 = __shfl(sle, e + 1);
                int s2 = __shfl(sle, e + 2), s3 = __shfl(sle, e + 3);
                ushort2 v0 = *(const ushort2*)&Y1[(size_t)s0 * 128 + lane * 2];
                ushort2 v1 = *(const ushort2*)&Y1[(size_t)s1 * 128 + lane * 2];
                ushort2 v2 = *(const ushort2*)&Y1[(size_t)s2 * 128 + lane * 2];
                ushort2 v3 = *(const ushort2*)&Y1[(size_t)s3 * 128 + lane * 2];
                a0 += bf2f(v0.x) + bf2f(v1.x) + bf2f(v2.x) + bf2f(v3.x);
                a1 += bf2f(v0.y) + bf2f(v1.y) + bf2f(v2.y) + bf2f(v3.y);
            }
            for (; e < d; ++e) {
                int s = __shfl(sle, e);
                ushort2 v = *(const ushort2*)&Y1[(size_t)s * 128 + lane * 2];
                a0 += bf2f(v.x); a1 += bf2f(v.y);
            }
            a0 = fmaxf(a0, 0.f);
            a1 = fmaxf(a1, 0.f);
        }
        *(float2*)&sA[r * 128 + lane * 2] = make_float2(a0, a1);
    }
    __syncthreads();
    gemm128_phase(sA, Wh, Y2, row0, t, N);
}

// ==================== K3: agg(ln*Y2)*rn, relu, @ W2 ====================
static __global__ __launch_bounds__(256) void agg3_gemm40_kernel(
    const unsigned short* __restrict__ Y2, const float* __restrict__ W2,
    unsigned short* __restrict__ Y3,
    const int* __restrict__ csr, const int* __restrict__ indeg,
    const int* __restrict__ outdeg, int N) {
    __shared__ float sA[64 * 128];
    int t = threadIdx.x;
    int w = t >> 6, lane = t & 63;
    int row0 = blockIdx.x * 64;

    for (int i = 0; i < 16; ++i) {
        int r = w * 16 + i;
        int node = row0 + r;
        float a0 = 0.f, a1 = 0.f;
        if (node < N) {
            int d = indeg[node];
            int dc = d > MAXDEG ? MAXDEG : d;
            int sle = 0;
            float lnle = 0.f;
            if (lane < dc) {
                sle = csr[node * MAXDEG + lane];
                int od = outdeg[sle];
                lnle = rsqrtf((float)(od > 1 ? od : 1));
            }
            int e = 0;
            for (; e + 4 <= dc; e += 4) {
                int s0 = __shfl(sle, e), s1 = __shfl(sle, e + 1);
                int s2 = __shfl(sle, e + 2), s3 = __shfl(sle, e + 3);
                float l0 = __shfl(lnle, e), l1 = __shfl(lnle, e + 1);
                float l2 = __shfl(lnle, e + 2), l3 = __shfl(lnle, e + 3);
                ushort2 v0 = *(const ushort2*)&Y2[(size_t)s0 * 128 + lane * 2];
                ushort2 v1 = *(const ushort2*)&Y2[(size_t)s1 * 128 + lane * 2];
                ushort2 v2 = *(const ushort2*)&Y2[(size_t)s2 * 128 + lane * 2];
                ushort2 v3 = *(const ushort2*)&Y2[(size_t)s3 * 128 + lane * 2];
                a0 += l0 * bf2f(v0.x) + l1 * bf2f(v1.x) + l2 * bf2f(v2.x) + l3 * bf2f(v3.x);
                a1 += l0 * bf2f(v0.y) + l1 * bf2f(v1.y) + l2 * bf2f(v2.y) + l3 * bf2f(v3.y);
            }
            for (; e < dc; ++e) {
                int s = __shfl(sle, e);
                float l = __shfl(lnle, e);
                ushort2 v = *(const ushort2*)&Y2[(size_t)s * 128 + lane * 2];
                a0 += l * bf2f(v.x); a1 += l * bf2f(v.y);
            }
            float rn = rsqrtf((float)(d > 1 ? d : 1));
            a0 = fmaxf(a0 * rn, 0.f);
            a1 = fmaxf(a1 * rn, 0.f);
        }
        *(float2*)&sA[r * 128 + lane * 2] = make_float2(a0, a1);
    }
    __syncthreads();
    gemm40_phase(sA, W2, Y3, row0, t, N);
}

// ========== K4: agg(ln*Y3)*rn + b2 + log_softmax ==========
static __global__ __launch_bounds__(256) void agg40_lsm_kernel(
    const unsigned short* __restrict__ Y3, const float* __restrict__ b2,
    const int* __restrict__ csr, const int* __restrict__ indeg,
    const int* __restrict__ outdeg, float* __restrict__ out, int N) {
    int t = threadIdx.x;
    int node = blockIdx.x * 4 + (t >> 6);
    if (node >= N) return;
    int lane = t & 63;
    int grp = lane >> 4;   // 0..3  : edge group
    int sub = lane & 15;   // 0..15 : dim group (10 active)
    int d = indeg[node];
    int dc = d > MAXDEG ? MAXDEG : d;

    float a0 = 0.f, a1 = 0.f, a2 = 0.f, a3 = 0.f;
    if (sub < 10) {
        for (int e = grp; e < dc; e += 4) {
            int s = csr[node * MAXDEG + e];
            int od = outdeg[s];
            float ln = rsqrtf((float)(od > 1 ? od : 1));
            ushort4 v = *(const ushort4*)&Y3[(size_t)s * 40 + sub * 4];
            a0 += ln * bf2f(v.x); a1 += ln * bf2f(v.y);
            a2 += ln * bf2f(v.z); a3 += ln * bf2f(v.w);
        }
    }
    a0 += __shfl_xor(a0, 16); a0 += __shfl_xor(a0, 32);
    a1 += __shfl_xor(a1, 16); a1 += __shfl_xor(a1, 32);
    a2 += __shfl_xor(a2, 16); a2 += __shfl_xor(a2, 32);
    a3 += __shfl_xor(a3, 16); a3 += __shfl_xor(a3, 32);

    float rs = rsqrtf((float)(d > 1 ? d : 1));
    float x0 = 0.f, x1 = 0.f, x2 = 0.f, x3 = 0.f;
    float mx = -INFINITY;
    if (sub < 10) {
        float4 b = *(const float4*)&b2[sub * 4];
        x0 = a0 * rs + b.x;
        x1 = a1 * rs + b.y;
        x2 = a2 * rs + b.z;
        x3 = a3 * rs + b.w;
        mx = fmaxf(fmaxf(x0, x1), fmaxf(x2, x3));
    }
#pragma unroll
    for (int o = 1; o < 16; o <<= 1) mx = fmaxf(mx, __shfl_xor(mx, o));
    float ex = 0.f;
    if (sub < 10)
        ex = expf(x0 - mx) + expf(x1 - mx) + expf(x2 - mx) + expf(x3 - mx);
#pragma unroll
    for (int o = 1; o < 16; o <<= 1) ex += __shfl_xor(ex, o);
    float ls = logf(ex) + mx;
    if (sub < 10 && grp == 0)
        *(float4*)&out[(size_t)node * 40 + sub * 4] =
            make_float4(x0 - ls, x1 - ls, x2 - ls, x3 - ls);
}

// -------------------- launch --------------------

extern "C" void kernel_launch(void* const* d_in, const int* in_sizes, int n_in,
                              void* d_out, int out_size, void* d_ws, size_t ws_size,
                              hipStream_t stream) {
    const float* features = (const float*)d_in[0];
    const int* src = (const int*)d_in[1];
    const int* dst = (const int*)d_in[2];
    const float* W1 = (const float*)d_in[3];
    const float* Wh = (const float*)d_in[4];
    const float* W2 = (const float*)d_in[5];
    const float* b2 = (const float*)d_in[6];
    float* out = (float*)d_out;

    const int N = in_sizes[0] / 128;
    const int E = in_sizes[1];

    char* p = (char*)d_ws;
    auto carve = [&](size_t bytes) {
        char* q = p;
        p += (bytes + 255) & ~(size_t)255;
        return q;
    };
    unsigned short* bufY1 = (unsigned short*)carve((size_t)N * 128 * 2);
    unsigned short* bufY2 = (unsigned short*)carve((size_t)N * 128 * 2);
    unsigned short* bufY3 = (unsigned short*)carve((size_t)N * 40 * 2);
    int* csr = (int*)carve((size_t)N * MAXDEG * 4);
    int* outdeg = (int*)carve((size_t)N * 4);
    int* indeg = (int*)carve((size_t)N * 4);
    (void)ws_size; (void)n_in; (void)out_size;

    hipMemsetAsync(outdeg, 0, (size_t)N * 4, stream);
    hipMemsetAsync(indeg, 0, (size_t)N * 4, stream);

    int gG = (N + 63) / 64;          // gemm blocks
    int gE = (E + 2047) / 2048;      // edge blocks (8 edges/thread)
    // K1: CSR build (indeg) || gemm1
    csr_gemm1_kernel<<<gG + gE, 256, 0, stream>>>(
        features, W1, bufY1, src, dst, indeg, csr, N, E, gG, gE);
    // K2: outdeg histogram || Y2' = relu(agg(Y1)) @ Wh
    hist_agggemm2_kernel<<<gG + gE, 256, 0, stream>>>(
        bufY1, Wh, bufY2, csr, indeg, src, outdeg, N, E, gG, gE);
    // K3: Y3' = relu(agg(ln*Y2') * rn) @ W2
    agg3_gemm40_kernel<<<gG, 256, 0, stream>>>(bufY2, W2, bufY3, csr, indeg, outdeg, N);
    // K4: out = log_softmax(agg(ln*Y3') * rn + b2)
    agg40_lsm_kernel<<<(N + 3) / 4, 256, 0, stream>>>(bufY3, b2, csr, indeg, outdeg, out, N);
}